// Round 6
// baseline (241.571 us; speedup 1.0000x reference)
//
#include <hip/hip_runtime.h>

#define NB 15
#define NV 17          // focal, cp, 15 bins
#define GRID 2048      // 8 blocks/CU on 256 CUs
#define BLOCK 256

// partials layout in ws: partials[j * GRID + block], j in [0,17)

// Pure arithmetic per element; histogram add happens in kernel body so the
// atomicAdd target is syntactically the __shared__ array (ds_add_f32 path).
__device__ __forceinline__ int elem_math(float pk, float uk, int tk,
                                         float& facc, float& cacc, float& v)
{
    bool pos = (tk == 1);
    float q = 1.0f - pk;             // = pt (neg) and t-p (pos)

    // focal: -alpha * (1-pt)^2 * log(pt + 1e-12), alpha = pos?1:2
    float pt = pos ? pk : q;
    float om = 1.0f - pt;
    float s  = om * om;
    float sa = pos ? s : (s + s);
    facc = fmaf(-sa, __logf(pt + 1e-12f), facc);

    // calibration penalty
    float w  = 1.0f - uk;
    float a  = (pk < 0.7f) ? uk * uk : 0.0f;
    float b2 = (pk > 0.7f) ? w * w : 0.0f;
    cacc += pos ? a : b2;

    // ECE: bin = clip(ceil(p*15)-1, 0, 14); v = t - p
    int b = (int)ceilf(pk * 15.0f) - 1;
    b = (b < 0) ? 0 : ((b > NB - 1) ? NB - 1 : b);
    v = pos ? q : -pk;
    return b;
}

__global__ __launch_bounds__(BLOCK) void fcl_main(
    const float* __restrict__ p_hat,
    const float* __restrict__ u_hat,
    const int*   __restrict__ targets,
    float* __restrict__ partials,
    int n4, int n)
{
    // lane-private histogram slices; stride 15 coprime with 32 banks
    __shared__ float sbins[BLOCK * NB];
    #pragma unroll
    for (int j = 0; j < NB; ++j) sbins[j * BLOCK + threadIdx.x] = 0.0f;
    __syncthreads();
    const int sl = threadIdx.x * NB;

    float facc = 0.0f, cacc = 0.0f;

    const float4* __restrict__ p4 = (const float4*)p_hat;
    const float4* __restrict__ u4 = (const float4*)u_hat;
    const int4*   __restrict__ t4 = (const int4*)targets;

    const int stride = GRID * BLOCK;
    int i = blockIdx.x * BLOCK + threadIdx.x;

    // 2x unrolled grid-stride (n=16.7M: exactly 4 iterations, no remainder)
    for (; i + stride < n4; i += 2 * stride) {
        float4 p0 = p4[i];          float4 p1 = p4[i + stride];
        float4 u0 = u4[i];          float4 u1 = u4[i + stride];
        int4   t0 = t4[i];          int4   t1 = t4[i + stride];
        #pragma unroll
        for (int k = 0; k < 4; ++k) {
            float v; int b = elem_math((&p0.x)[k], (&u0.x)[k], (&t0.x)[k],
                                       facc, cacc, v);
            atomicAdd(&sbins[sl + b], v);      // ds_add_f32, no return
        }
        #pragma unroll
        for (int k = 0; k < 4; ++k) {
            float v; int b = elem_math((&p1.x)[k], (&u1.x)[k], (&t1.x)[k],
                                       facc, cacc, v);
            atomicAdd(&sbins[sl + b], v);
        }
    }
    for (; i < n4; i += stride) {
        float4 p0 = p4[i]; float4 u0 = u4[i]; int4 t0 = t4[i];
        #pragma unroll
        for (int k = 0; k < 4; ++k) {
            float v; int b = elem_math((&p0.x)[k], (&u0.x)[k], (&t0.x)[k],
                                       facc, cacc, v);
            atomicAdd(&sbins[sl + b], v);
        }
    }

    // scalar tail (n not multiple of 4)
    if (blockIdx.x == 0 && threadIdx.x == 0) {
        for (int j = n4 * 4; j < n; ++j) {
            float v; int b = elem_math(p_hat[j], u_hat[j], targets[j],
                                       facc, cacc, v);
            atomicAdd(&sbins[sl + b], v);
        }
    }

    __syncthreads();

    // gather own slice + wave-64 shuffle reduction of all 17 values
    float vals[NV];
    vals[0] = facc; vals[1] = cacc;
    #pragma unroll
    for (int j = 0; j < NB; ++j) vals[2 + j] = sbins[sl + j];

    #pragma unroll
    for (int off = 32; off > 0; off >>= 1) {
        #pragma unroll
        for (int j = 0; j < NV; ++j)
            vals[j] += __shfl_down(vals[j], off, 64);
    }

    __shared__ float lds[BLOCK / 64][NV];
    const int wave = threadIdx.x >> 6;
    const int lane = threadIdx.x & 63;
    if (lane == 0) {
        #pragma unroll
        for (int j = 0; j < NV; ++j) lds[wave][j] = vals[j];
    }
    __syncthreads();

    if (threadIdx.x < NV) {
        float s = 0.0f;
        #pragma unroll
        for (int w = 0; w < BLOCK / 64; ++w) s += lds[w][threadIdx.x];
        partials[threadIdx.x * GRID + blockIdx.x] = s;
    }
}

__global__ __launch_bounds__(1024) void fcl_final(
    const float* __restrict__ partials,
    float* __restrict__ out, float inv_n, int grid)
{
    const int t = threadIdx.x;
    float v[NV];
    #pragma unroll
    for (int j = 0; j < NV; ++j) {
        float s = 0.0f;
        for (int i = t; i < grid; i += 1024) s += partials[j * grid + i];
        v[j] = s;
    }

    #pragma unroll
    for (int off = 32; off > 0; off >>= 1) {
        #pragma unroll
        for (int j = 0; j < NV; ++j)
            v[j] += __shfl_down(v[j], off, 64);
    }

    __shared__ float lds[16][NV];
    const int wave = t >> 6;
    const int lane = t & 63;
    if (lane == 0) {
        #pragma unroll
        for (int j = 0; j < NV; ++j) lds[wave][j] = v[j];
    }
    __syncthreads();

    if (t == 0) {
        float s[NV];
        #pragma unroll
        for (int j = 0; j < NV; ++j) s[j] = 0.0f;
        for (int w = 0; w < 16; ++w)
            #pragma unroll
            for (int j = 0; j < NV; ++j) s[j] += lds[w][j];
        float e = 0.0f;
        #pragma unroll
        for (int b = 0; b < NB; ++b) e += fabsf(s[2 + b]);
        out[0] = (s[0] + 6.0f * s[1] + 5.0f * e) * inv_n;
    }
}

extern "C" void kernel_launch(void* const* d_in, const int* in_sizes, int n_in,
                              void* d_out, int out_size, void* d_ws, size_t ws_size,
                              hipStream_t stream) {
    const float* p = (const float*)d_in[0];
    const float* u = (const float*)d_in[1];
    const int*   t = (const int*)d_in[2];
    float* out = (float*)d_out;
    float* ws  = (float*)d_ws;

    const int n  = in_sizes[0];
    const int n4 = n / 4;

    fcl_main<<<GRID, BLOCK, 0, stream>>>(p, u, t, ws, n4, n);
    fcl_final<<<1, 1024, 0, stream>>>(ws, out, 1.0f / (float)n, GRID);
}

// Round 7
// 217.897 us; speedup vs baseline: 1.1086x; 1.1086x over previous
//
#include <hip/hip_runtime.h>

#define NB 15
#define NV 17          // focal, cp, 15 bins
#define GRID 2048      // 8 blocks/CU on 256 CUs
#define BLOCK 256

// partials layout in ws: partials[j * GRID + block], j in [0,17)

__device__ __forceinline__ void process_elem(float pk, float uk, int tk,
                                             float& facc, float& cacc,
                                             float* bins)
{
    bool pos = (tk == 1);
    float q = 1.0f - pk;             // = pt (neg) and t-p (pos)

    // focal: -alpha * (1-pt)^2 * log(pt + 1e-12), alpha = pos?1:2
    float pt = pos ? pk : q;
    float om = 1.0f - pt;
    float s  = om * om;
    float sa = pos ? s : (s + s);
    facc = fmaf(-sa, __logf(pt + 1e-12f), facc);

    // calibration penalty
    float w  = 1.0f - uk;
    float a  = (pk < 0.7f) ? uk * uk : 0.0f;
    float b2 = (pk > 0.7f) ? w * w : 0.0f;
    cacc += pos ? a : b2;

    // ECE: bin = clip(ceil(p*15)-1, 0, 14); v = t - p
    int b = (int)ceilf(pk * 15.0f) - 1;
    b = (b < 0) ? 0 : ((b > NB - 1) ? NB - 1 : b);
    float v = pos ? q : -pk;
    #pragma unroll
    for (int j = 0; j < NB; ++j)
        bins[j] += (b == j) ? v : 0.0f;
}

// (BLOCK, 4): min 4 waves/EU -> 128-VGPR cap. WITHOUT the 2nd arg the
// compiler targets 8 waves/EU (64-VGPR cap) and SPILLS bins[15] to scratch
// -- that scratch RMW was the 80us wall in R2/R4/R5 (VGPR<=40, WRITE_SIZE
// scaling with pressure, dur flat vs occupancy & L3 residency).
__global__ __launch_bounds__(BLOCK, 4) void fcl_main(
    const float* __restrict__ p_hat,
    const float* __restrict__ u_hat,
    const int*   __restrict__ targets,
    float* __restrict__ partials,
    int n4, int n)
{
    float bins[NB];
    #pragma unroll
    for (int j = 0; j < NB; ++j) bins[j] = 0.0f;
    float facc = 0.0f, cacc = 0.0f;

    const float4* __restrict__ p4 = (const float4*)p_hat;
    const float4* __restrict__ u4 = (const float4*)u_hat;
    const int4*   __restrict__ t4 = (const int4*)targets;

    const int stride = GRID * BLOCK;
    int i = blockIdx.x * BLOCK + threadIdx.x;

    // 2x unrolled grid-stride (n=16.7M: exactly 4 iterations, no remainder)
    for (; i + stride < n4; i += 2 * stride) {
        float4 p0 = p4[i];          float4 p1 = p4[i + stride];
        float4 u0 = u4[i];          float4 u1 = u4[i + stride];
        int4   t0 = t4[i];          int4   t1 = t4[i + stride];
        #pragma unroll
        for (int k = 0; k < 4; ++k)
            process_elem((&p0.x)[k], (&u0.x)[k], (&t0.x)[k], facc, cacc, bins);
        #pragma unroll
        for (int k = 0; k < 4; ++k)
            process_elem((&p1.x)[k], (&u1.x)[k], (&t1.x)[k], facc, cacc, bins);
    }
    for (; i < n4; i += stride) {
        float4 p0 = p4[i]; float4 u0 = u4[i]; int4 t0 = t4[i];
        #pragma unroll
        for (int k = 0; k < 4; ++k)
            process_elem((&p0.x)[k], (&u0.x)[k], (&t0.x)[k], facc, cacc, bins);
    }

    // scalar tail (n not multiple of 4)
    if (blockIdx.x == 0 && threadIdx.x == 0) {
        for (int j = n4 * 4; j < n; ++j)
            process_elem(p_hat[j], u_hat[j], targets[j], facc, cacc, bins);
    }

    // wave-64 shuffle reduction of all 17 values
    float vals[NV];
    vals[0] = facc; vals[1] = cacc;
    #pragma unroll
    for (int j = 0; j < NB; ++j) vals[2 + j] = bins[j];

    #pragma unroll
    for (int off = 32; off > 0; off >>= 1) {
        #pragma unroll
        for (int j = 0; j < NV; ++j)
            vals[j] += __shfl_down(vals[j], off, 64);
    }

    __shared__ float lds[BLOCK / 64][NV];
    const int wave = threadIdx.x >> 6;
    const int lane = threadIdx.x & 63;
    if (lane == 0) {
        #pragma unroll
        for (int j = 0; j < NV; ++j) lds[wave][j] = vals[j];
    }
    __syncthreads();

    if (threadIdx.x < NV) {
        float s = 0.0f;
        #pragma unroll
        for (int w = 0; w < BLOCK / 64; ++w) s += lds[w][threadIdx.x];
        partials[threadIdx.x * GRID + blockIdx.x] = s;
    }
}

__global__ __launch_bounds__(1024) void fcl_final(
    const float* __restrict__ partials,
    float* __restrict__ out, float inv_n, int grid)
{
    const int t = threadIdx.x;
    float v[NV];
    #pragma unroll
    for (int j = 0; j < NV; ++j) {
        float s = 0.0f;
        for (int i = t; i < grid; i += 1024) s += partials[j * grid + i];
        v[j] = s;
    }

    #pragma unroll
    for (int off = 32; off > 0; off >>= 1) {
        #pragma unroll
        for (int j = 0; j < NV; ++j)
            v[j] += __shfl_down(v[j], off, 64);
    }

    __shared__ float lds[16][NV];
    const int wave = t >> 6;
    const int lane = t & 63;
    if (lane == 0) {
        #pragma unroll
        for (int j = 0; j < NV; ++j) lds[wave][j] = v[j];
    }
    __syncthreads();

    if (t == 0) {
        float s[NV];
        #pragma unroll
        for (int j = 0; j < NV; ++j) s[j] = 0.0f;
        for (int w = 0; w < 16; ++w)
            #pragma unroll
            for (int j = 0; j < NV; ++j) s[j] += lds[w][j];
        float e = 0.0f;
        #pragma unroll
        for (int b = 0; b < NB; ++b) e += fabsf(s[2 + b]);
        out[0] = (s[0] + 6.0f * s[1] + 5.0f * e) * inv_n;
    }
}

extern "C" void kernel_launch(void* const* d_in, const int* in_sizes, int n_in,
                              void* d_out, int out_size, void* d_ws, size_t ws_size,
                              hipStream_t stream) {
    const float* p = (const float*)d_in[0];
    const float* u = (const float*)d_in[1];
    const int*   t = (const int*)d_in[2];
    float* out = (float*)d_out;
    float* ws  = (float*)d_ws;

    const int n  = in_sizes[0];
    const int n4 = n / 4;

    fcl_main<<<GRID, BLOCK, 0, stream>>>(p, u, t, ws, n4, n);
    fcl_final<<<1, 1024, 0, stream>>>(ws, out, 1.0f / (float)n, GRID);
}